// Round 1
// baseline (10052.421 us; speedup 1.0000x reference)
//
#include <hip/hip_runtime.h>
#include <stdint.h>

#define B_ 256
#define T_ 512
#define DIN 512
#define H_ 1024
#define BT (B_*T_)
#define G3 (3*H_)

typedef unsigned short u16;
typedef unsigned int u32;
typedef unsigned long long u64;
typedef __attribute__((ext_vector_type(8))) __bf16 bf16x8;
typedef __attribute__((ext_vector_type(4))) float f4;

__device__ __forceinline__ u16 f2bf(float f){
  u32 u = __float_as_uint(f);
  u32 r = u + 0x7fffu + ((u>>16)&1u);
  return (u16)(r>>16);
}
__device__ __forceinline__ float bf2f(u16 u){ return __uint_as_float(((u32)u)<<16); }
__device__ __forceinline__ float sigm(float x){ return 1.f/(1.f+__expf(-x)); }
__device__ __forceinline__ float tanh_f(float x){
  x = fminf(fmaxf(x, -15.f), 15.f);
  float e = __expf(2.f*x);
  return (e-1.f)/(e+1.f);
}
__device__ __forceinline__ void gload_lds16(const u16* g, u16* l){
  __builtin_amdgcn_global_load_lds((const __attribute__((address_space(1))) void*)g,
                                   (__attribute__((address_space(3))) void*)l, 16, 0, 0);
}
__device__ __forceinline__ f4 mfma16(bf16x8 a, bf16x8 b, f4 c){
  return __builtin_amdgcn_mfma_f32_16x16x32_bf16(a, b, c, 0, 0, 0);
}

// ---------------- cast f32 -> bf16, 8 elems/thread ----------------
__global__ __launch_bounds__(256) void k_cast(const float* __restrict__ s,
                                              u16* __restrict__ d, int n8){
  int i = blockIdx.x*256 + threadIdx.x;
  int st = gridDim.x*256;
  for (; i < n8; i += st){
    float4 a = ((const float4*)s)[i*2+0];
    float4 b = ((const float4*)s)[i*2+1];
    uint4 o;
    o.x = (u32)f2bf(a.x) | ((u32)f2bf(a.y)<<16);
    o.y = (u32)f2bf(a.z) | ((u32)f2bf(a.w)<<16);
    o.z = (u32)f2bf(b.x) | ((u32)f2bf(b.y)<<16);
    o.w = (u32)f2bf(b.z) | ((u32)f2bf(b.w)<<16);
    ((uint4*)d)[i] = o;
  }
}

// ---------------- phase 1: x = tanh(in@Wi^T+bi+cbi) * sigm(in@Wg^T+bg+cbg) ----------------
// 128x64 tile, two B panels, BK=32, 4 waves (2x2), K=512
__global__ __launch_bounds__(256) void k_phase1(
    const u16* __restrict__ A, const u16* __restrict__ Wi, const u16* __restrict__ Wg,
    const float* __restrict__ bin, const float* __restrict__ bgt,
    const float* __restrict__ cbi, const float* __restrict__ cbg,
    u16* __restrict__ X){
  __shared__ u16 As[128*32];
  __shared__ u16 Bi[64*32];
  __shared__ u16 Bg[64*32];
  int tid = threadIdx.x;
  int lane = tid & 63, wave = tid >> 6;
  int l15 = lane & 15, l4 = lane >> 4;
  int m0 = (blockIdx.x & 1023)*128;
  int n0 = (blockIdx.x >> 10)*64;
  int mo = (wave&1)*64, no = (wave>>1)*32;
  f4 acc1[4][2] = {}; f4 acc2[4][2] = {};
  for (int k0 = 0; k0 < DIN; k0 += 32){
    int u = tid;
    gload_lds16(A + (m0 + (u>>2))*DIN + k0 + (u&3)*8, As + wave*512);
    u = 256 + tid;
    gload_lds16(A + (m0 + (u>>2))*DIN + k0 + (u&3)*8, As + (4+wave)*512);
    u = tid;
    gload_lds16(Wi + (n0 + (u>>2))*DIN + k0 + (u&3)*8, Bi + wave*512);
    gload_lds16(Wg + (n0 + (u>>2))*DIN + k0 + (u&3)*8, Bg + wave*512);
    __syncthreads();
    bf16x8 a[4], b1[2], b2[2];
    #pragma unroll
    for (int mt=0; mt<4; mt++) a[mt] = *(const bf16x8*)&As[(mo+mt*16+l15)*32 + l4*8];
    #pragma unroll
    for (int nt=0; nt<2; nt++){
      b1[nt] = *(const bf16x8*)&Bi[(no+nt*16+l15)*32 + l4*8];
      b2[nt] = *(const bf16x8*)&Bg[(no+nt*16+l15)*32 + l4*8];
    }
    #pragma unroll
    for (int mt=0; mt<4; mt++)
      #pragma unroll
      for (int nt=0; nt<2; nt++){
        acc1[mt][nt] = mfma16(a[mt], b1[nt], acc1[mt][nt]);
        acc2[mt][nt] = mfma16(a[mt], b2[nt], acc2[mt][nt]);
      }
    __syncthreads();
  }
  #pragma unroll
  for (int mt=0; mt<4; mt++)
   #pragma unroll
   for (int nt=0; nt<2; nt++)
    #pragma unroll
    for (int i=0; i<4; i++){
      int m = m0 + mo + mt*16 + l4*4 + i;
      int n = n0 + no + nt*16 + l15;
      int b = m >> 9;
      float xl = acc1[mt][nt][i] + bin[n] + cbi[b*H_ + n];
      float gl = acc2[mt][nt][i] + bgt[n] + cbg[b*H_ + n];
      X[(size_t)m*H_ + n] = f2bf(tanh_f(xl) * sigm(gl));
    }
}

// ---------------- phase 2: gi[t][b][:] = x@W_ih^T + b_ih  (bf16 out) ----------------
// 128x128 tile, BK=32, 4 waves (2x2), K=1024
__global__ __launch_bounds__(256) void k_phase2(
    const u16* __restrict__ X, const u16* __restrict__ W,
    const float* __restrict__ bih, u16* __restrict__ GI){
  __shared__ u16 As[128*32];
  __shared__ u16 Bs[128*32];
  int tid = threadIdx.x;
  int lane = tid & 63, wave = tid >> 6;
  int l15 = lane & 15, l4 = lane >> 4;
  int m0 = (blockIdx.x & 1023)*128;
  int n0 = (blockIdx.x >> 10)*128;
  int mo = (wave&1)*64, no = (wave>>1)*64;
  f4 acc[4][4] = {};
  for (int k0 = 0; k0 < H_; k0 += 32){
    int u = tid;
    gload_lds16(X + (m0 + (u>>2))*H_ + k0 + (u&3)*8, As + wave*512);
    gload_lds16(W + (n0 + (u>>2))*H_ + k0 + (u&3)*8, Bs + wave*512);
    u = 256 + tid;
    gload_lds16(X + (m0 + (u>>2))*H_ + k0 + (u&3)*8, As + (4+wave)*512);
    gload_lds16(W + (n0 + (u>>2))*H_ + k0 + (u&3)*8, Bs + (4+wave)*512);
    __syncthreads();
    bf16x8 a[4], b[4];
    #pragma unroll
    for (int t2=0; t2<4; t2++){
      a[t2] = *(const bf16x8*)&As[(mo+t2*16+l15)*32 + l4*8];
      b[t2] = *(const bf16x8*)&Bs[(no+t2*16+l15)*32 + l4*8];
    }
    #pragma unroll
    for (int mt=0; mt<4; mt++)
      #pragma unroll
      for (int nt=0; nt<4; nt++)
        acc[mt][nt] = mfma16(a[mt], b[nt], acc[mt][nt]);
    __syncthreads();
  }
  #pragma unroll
  for (int mt=0; mt<4; mt++)
   #pragma unroll
   for (int nt=0; nt<4; nt++)
    #pragma unroll
    for (int i=0; i<4; i++){
      int m = m0 + mo + mt*16 + l4*4 + i;
      int n = n0 + no + nt*16 + l15;
      int b = m >> 9, t = m & 511;
      GI[((size_t)t*B_ + b)*G3 + n] = f2bf(acc[mt][nt][i] + bih[n]);
    }
}

// ---------------- scan: persistent GRU over T with W_hh resident in registers ----------------
// 256 blocks: bi=blockIdx%8 (batch group of 32 rows), ji=blockIdx/8 (32-col hidden tile).
// Each block: gh tile (32 x 96) = h[32x1024] @ Whh_slice^T, K split across 4 waves.
__global__ __launch_bounds__(256,1) void k_scan(
    const u16* __restrict__ GI, const u16* __restrict__ Whh,
    const float* __restrict__ bhh, const float* __restrict__ mask,
    u16* __restrict__ hbuf, int* __restrict__ cnt, float* __restrict__ Y){
  __shared__ u16 hs[32*1024];          // 64 KiB; aliased as reduction buffer
  float* red = (float*)hs;             // [4][32][100] = 51200 B (padded stride vs bank conflicts)
  int tid = threadIdx.x;
  int lane = tid & 63, wave = tid >> 6;
  int l15 = lane & 15, l4 = lane >> 4;
  int bi = blockIdx.x & 7, ji = blockIdx.x >> 3;
  int b0 = bi*32, j0 = ji*32;
  int kw = wave*256;                   // K-split window per wave

  // resident W_hh fragments: [6 n-tiles][8 k-steps], 192 VGPRs/wave
  bf16x8 wf[6][8];
  #pragma unroll
  for (int nt=0; nt<6; nt++){
    int wrow = (nt>>1)*H_ + j0 + (nt&1)*16 + l15;
    #pragma unroll
    for (int ks=0; ks<8; ks++)
      wf[nt][ks] = *(const bf16x8*)&Whh[(size_t)wrow*H_ + kw + ks*32 + l4*8];
  }

  int urow = tid >> 3;                 // 0..31 batch row (local)
  int c0 = (tid & 7)*4;                // 0..28 hidden col (local)
  float bh[3][4];
  #pragma unroll
  for (int g=0; g<3; g++)
    #pragma unroll
    for (int ci=0; ci<4; ci++)
      bh[g][ci] = bhh[g*H_ + j0 + c0 + ci];
  float hreg[4] = {0.f,0.f,0.f,0.f};
  const float* mr = mask + (b0+urow)*T_;

  for (int t=0; t<T_; t++){
    if (tid==0 && t>0){
      u32 it = 0;
      while (__hip_atomic_load(&cnt[t*8+bi], __ATOMIC_RELAXED, __HIP_MEMORY_SCOPE_AGENT) < 32){
        __builtin_amdgcn_s_sleep(2);
        if (++it > 10000000u) break;   // bail-out instead of hard hang
      }
      (void)__hip_atomic_load(&cnt[t*8+bi], __ATOMIC_ACQUIRE, __HIP_MEMORY_SCOPE_AGENT);
    }
    __syncthreads();
    // stage h[32][1024] bf16, XOR-swizzled 16B blocks (blk ^= row&7)
    {
      const u16* hc = hbuf + (t&1)*(B_*H_) + b0*H_;
      #pragma unroll
      for (int i=0; i<16; i++){
        int u = i*256 + tid;
        int row = u >> 7, c16 = u & 127;
        uint4 v = *(const uint4*)&hc[row*H_ + c16*8];
        *(uint4*)&hs[row*1024 + ((c16 ^ (row&7))<<3)] = v;
      }
    }
    __syncthreads();
    f4 acc[2][6] = {};
    #pragma unroll
    for (int ks=0; ks<8; ks++){
      bf16x8 a[2];
      #pragma unroll
      for (int mt=0; mt<2; mt++){
        int row = mt*16 + l15;
        int kk = kw + ks*32 + l4*8;
        a[mt] = *(const bf16x8*)&hs[row*1024 + (((kk>>3) ^ (row&7))<<3)];
      }
      #pragma unroll
      for (int mt=0; mt<2; mt++)
        #pragma unroll
        for (int nt=0; nt<6; nt++)
          acc[mt][nt] = mfma16(a[mt], wf[nt][ks], acc[mt][nt]);
    }
    __syncthreads();                   // MFMA reads done before red overwrites hs
    #pragma unroll
    for (int mt=0; mt<2; mt++)
      #pragma unroll
      for (int nt=0; nt<6; nt++)
        #pragma unroll
        for (int i=0; i<4; i++)
          red[(wave*32 + mt*16 + l4*4 + i)*100 + nt*16 + l15] = acc[mt][nt][i];
    __syncthreads();
    // GRU elementwise update: each thread owns 4 h elements
    {
      float gh[3][4];
      #pragma unroll
      for (int g=0; g<3; g++)
        #pragma unroll
        for (int ci=0; ci<4; ci++){
          int col = g*32 + c0 + ci;
          gh[g][ci] = red[(0*32+urow)*100 + col] + red[(1*32+urow)*100 + col]
                    + red[(2*32+urow)*100 + col] + red[(3*32+urow)*100 + col];
        }
      const u16* gib = GI + ((size_t)t*B_ + (b0+urow))*G3 + j0 + c0;
      float msk = mr[t];
      u16 hb[4];
      #pragma unroll
      for (int ci=0; ci<4; ci++){
        float ir  = bf2f(gib[0*H_ + ci]);
        float iz  = bf2f(gib[1*H_ + ci]);
        float in_ = bf2f(gib[2*H_ + ci]);
        float r = sigm(ir + gh[0][ci] + bh[0][ci]);
        float z = sigm(iz + gh[1][ci] + bh[1][ci]);
        float n = tanh_f(in_ + r*(gh[2][ci] + bh[2][ci]));
        float hn = (1.f - z)*n + z*hreg[ci];
        hreg[ci] = (msk > 0.5f) ? hn : hreg[ci];
        hb[ci] = f2bf(hreg[ci]);
      }
      float4 yv; yv.x = hreg[0]; yv.y = hreg[1]; yv.z = hreg[2]; yv.w = hreg[3];
      *(float4*)&Y[((size_t)(b0+urow)*T_ + t)*H_ + j0 + c0] = yv;
      u64 pk = (u64)hb[0] | ((u64)hb[1]<<16) | ((u64)hb[2]<<32) | ((u64)hb[3]<<48);
      __hip_atomic_store((u64*)&hbuf[((t+1)&1)*(B_*H_) + (b0+urow)*H_ + j0 + c0], pk,
                         __ATOMIC_RELAXED, __HIP_MEMORY_SCOPE_AGENT);
    }
    __syncthreads();                   // barrier drains all waves' sc1 stores
    if (tid==0)
      __hip_atomic_fetch_add(&cnt[(t+1)*8+bi], 1, __ATOMIC_RELEASE, __HIP_MEMORY_SCOPE_AGENT);
  }
}

// ---------------- LayerNorm over H, in-place on Y ----------------
__global__ __launch_bounds__(256) void k_ln(float* __restrict__ Y,
                                            const float* __restrict__ g,
                                            const float* __restrict__ b){
  int row = blockIdx.x, tid = threadIdx.x;
  float4 v = ((const float4*)(Y + (size_t)row*H_))[tid];
  float s = v.x+v.y+v.z+v.w;
  float q = v.x*v.x+v.y*v.y+v.z*v.z+v.w*v.w;
  #pragma unroll
  for (int off=32; off; off>>=1){ s += __shfl_down(s, off); q += __shfl_down(q, off); }
  __shared__ float ss[4], qq[4];
  int wave = tid >> 6;
  if ((tid&63)==0){ ss[wave]=s; qq[wave]=q; }
  __syncthreads();
  s = ss[0]+ss[1]+ss[2]+ss[3];
  q = qq[0]+qq[1]+qq[2]+qq[3];
  float mu = s*(1.f/H_);
  float var = q*(1.f/H_) - mu*mu;
  float rs = rsqrtf(var + 1e-5f);
  float4 gg = ((const float4*)g)[tid];
  float4 bb = ((const float4*)b)[tid];
  float4 o;
  o.x = (v.x-mu)*rs*gg.x + bb.x;
  o.y = (v.y-mu)*rs*gg.y + bb.y;
  o.z = (v.z-mu)*rs*gg.z + bb.z;
  o.w = (v.w-mu)*rs*gg.w + bb.w;
  ((float4*)(Y + (size_t)row*H_))[tid] = o;
}

extern "C" void kernel_launch(void* const* d_in, const int* in_sizes, int n_in,
                              void* d_out, int out_size, void* d_ws, size_t ws_size,
                              hipStream_t stream){
  const float* inputs = (const float*)d_in[0];
  const float* mask   = (const float*)d_in[1];
  const float* cbi    = (const float*)d_in[2];
  const float* cbg    = (const float*)d_in[3];
  const float* W_in   = (const float*)d_in[4];
  const float* b_in   = (const float*)d_in[5];
  const float* W_gate = (const float*)d_in[6];
  const float* b_gate = (const float*)d_in[7];
  const float* W_ih   = (const float*)d_in[8];
  const float* b_ih   = (const float*)d_in[9];
  const float* W_hh   = (const float*)d_in[10];
  const float* b_hh   = (const float*)d_in[11];
  const float* ln_g   = (const float*)d_in[12];
  const float* ln_b   = (const float*)d_in[13];

  char* ws = (char*)d_ws;
  size_t o = 0;
  u16* in_bf  = (u16*)(ws + o); o += (size_t)BT*DIN*2;      // 128 MiB
  u16* wi_bf  = (u16*)(ws + o); o += (size_t)H_*DIN*2;
  u16* wg_bf  = (u16*)(ws + o); o += (size_t)H_*DIN*2;
  u16* wih_bf = (u16*)(ws + o); o += (size_t)G3*H_*2;
  u16* whh_bf = (u16*)(ws + o); o += (size_t)G3*H_*2;
  u16* gi_bf  = (u16*)(ws + o); o += (size_t)T_*B_*G3*2;    // 768 MiB
  u16* hbuf   = (u16*)(ws + o); o += (size_t)2*B_*H_*2;
  int* cnt    = (int*)(ws + o); o += (size_t)(T_+1)*8*4;
  if (ws_size < o) return;  // workspace too small -> clean fail (tells us the limit)

  hipMemsetAsync(hbuf, 0, (size_t)2*B_*H_*2, stream);
  hipMemsetAsync(cnt, 0, (size_t)(T_+1)*8*4, stream);

  k_cast<<<2048,256,0,stream>>>(inputs, in_bf, BT*DIN/8);
  k_cast<<<256, 256,0,stream>>>(W_in,   wi_bf,  H_*DIN/8);
  k_cast<<<256, 256,0,stream>>>(W_gate, wg_bf,  H_*DIN/8);
  k_cast<<<1024,256,0,stream>>>(W_ih,   wih_bf, G3*H_/8);
  k_cast<<<1024,256,0,stream>>>(W_hh,   whh_bf, G3*H_/8);

  u16* X = (u16*)d_out;  // x (bf16, 256 MiB) staged in d_out; dead after phase2
  k_phase1<<<16384,256,0,stream>>>(in_bf, wi_bf, wg_bf, b_in, b_gate, cbi, cbg, X);
  k_phase2<<<24576,256,0,stream>>>(X, wih_bf, b_ih, gi_bf);
  k_scan<<<256,256,0,stream>>>(gi_bf, whh_bf, b_hh, mask, hbuf, cnt, (float*)d_out);
  k_ln<<<BT,256,0,stream>>>((float*)d_out, ln_g, ln_b);
}